// Round 1
// 185.554 us; speedup vs baseline: 1.0086x; 1.0086x over previous
//
#include <hip/hip_runtime.h>
#include <math.h>

#define NB 256
#define ND 512
#define NC 80
#define NSPLIT 8                 // blocks per anchor-equivalent in k_write grid
#define SLOT 32640               // max triplets per anchor (P=256 worst case)
#define KW_WAVES (NB * NSPLIT * 4)   // 8192 waves in k_write

// Module-scope device globals (no reliance on d_ws).
__device__ float g_x [NB * ND];           // normalized rows (fp32)
__device__ float g_xt[ND * NB];           // transposed copy
__device__ float g_sq[NB];                // fp32 sum of squares of normalized x
__device__ float g_ddneg[NB * NB];        // dist if negative else +INF
__device__ unsigned long long g_m[NB * 2];// label bitmasks (80 bits)
__device__ int   g_atot[NB];              // per-anchor quadruplet totals
__device__ int   g_cursor;                // dense triplet-list cursor
__device__ int4  g_trip[NB * SLOT];       // dense {j|k<<8, thr bits, toff, anchor}

// Integer inclusive scan over 256 threads: wave shfl-scan + 2-barrier combine.
// After call, wsum[0..3] hold per-wave totals (total = sum of the 4).
__device__ __forceinline__ int block_scan_int(int val, int* wsum) {
    int tid = threadIdx.x, wv = tid >> 6, ln = tid & 63;
    int v = val;
    #pragma unroll
    for (int off = 1; off < 64; off <<= 1) {
        int u = __shfl_up(v, off);
        v += (ln >= off) ? u : 0;
    }
    __syncthreads();                 // protect prior wsum readers
    if (ln == 63) wsum[wv] = v;
    __syncthreads();
    int add = 0;
    #pragma unroll
    for (int w = 0; w < 4; ++w) if (w < wv) add += wsum[w];
    return v + add;
}

// count = #{x in sorted[0..255] : x <= thr}; branchless bit-descent.
__device__ __forceinline__ int ubcount(const float* s, float thr) {
    int pos = 0;
    #pragma unroll
    for (int step = 128; step > 0; step >>= 1) {
        int np = pos + step;
        if (s[np - 1] <= thr) pos = np;
    }
    return pos;
}

// norm (byte-identical fp64 tree to prior rounds) + label masks + cursor reset
__global__ __launch_bounds__(256) void k_prep(const float* __restrict__ logits,
                                              const float* __restrict__ labels) {
    int b = blockIdx.x, tid = threadIdx.x;
    __shared__ double red[NB];
    if (b == 0 && tid == 0) g_cursor = 0;
    float v0 = logits[b * ND + tid];
    float v1 = logits[b * ND + 256 + tid];
    red[tid] = (double)(v0 * v0) + (double)(v1 * v1);
    __syncthreads();
    for (int off = 128; off > 0; off >>= 1) {
        if (tid < off) red[tid] += red[tid + off];
        __syncthreads();
    }
    float S = (float)red[0];
    float nrm = sqrtf(S);
    __syncthreads();
    float a0 = v0 / nrm;
    float a1 = v1 / nrm;
    g_x[b * ND + tid]          = a0;
    g_x[b * ND + 256 + tid]    = a1;
    g_xt[tid * NB + b]         = a0;
    g_xt[(tid + 256) * NB + b] = a1;
    red[tid] = (double)(a0 * a0) + (double)(a1 * a1);
    __syncthreads();
    for (int off = 128; off > 0; off >>= 1) {
        if (tid < off) red[tid] += red[tid + off];
        __syncthreads();
    }
    if (tid == 0) g_sq[b] = (float)red[0];
    int wv = tid >> 6, ln = tid & 63;
    if (wv == 0) {
        unsigned long long m0 = __ballot(labels[b * NC + ln] != 0.0f);
        if (ln == 0) g_m[2 * b] = m0;
    } else if (wv == 1) {
        bool p = (ln < 16) ? (labels[b * NC + 64 + ln] != 0.0f) : false;
        unsigned long long m1 = __ballot(p);
        if (ln == 0) g_m[2 * b + 1] = m1;
    }
}

// distance row (byte-identical fp64 math) + hybrid bitonic sort + dense tables
__global__ __launch_bounds__(256) void k_count() {
    __shared__ float xi[ND];
    __shared__ float s_dd[NB], s_sort[NB];
    __shared__ int s_w4[4], s_rowbase[NB], s_base;
    __shared__ short s_plist[NB];
    int i = blockIdx.x, tid = threadIdx.x;
    xi[tid]       = g_x[i * ND + tid];
    xi[tid + 256] = g_x[i * ND + 256 + tid];
    __syncthreads();
    double dot = 0.0;
    #pragma unroll 8
    for (int c = 0; c < ND; ++c)
        dot = fma((double)xi[c], (double)g_xt[c * NB + tid], dot);
    float dotf = (float)dot;
    float sm   = g_sq[i] + g_sq[tid];
    float d2   = sm - 2.0f * dotf;
    float dv   = sqrtf(d2 > 0.0f ? d2 : 0.0f);
    s_dd[tid] = dv;
    unsigned long long mi0 = g_m[2 * i],   mi1 = g_m[2 * i + 1];
    unsigned long long mt0 = g_m[2 * tid], mt1 = g_m[2 * tid + 1];
    bool shl   = ((mi0 & mt0) | (mi1 & mt1)) != 0ULL;
    bool isPos = shl && (tid != i);
    float ddneg = shl ? INFINITY : dv;
    g_ddneg[i * NB + tid] = ddneg;
    int incl = block_scan_int(isPos ? 1 : 0, s_w4);
    int P = s_w4[0] + s_w4[1] + s_w4[2] + s_w4[3];
    if (isPos) s_plist[incl - 1] = (short)tid;
    if (tid < P - 1) s_rowbase[tid] = tid * (P - 1) - (tid * (tid - 1)) / 2;
    // Hybrid bitonic (identical pairings/ops to prior rounds): j<=32 via shfl_xor.
    float v = ddneg;
    for (int k = 2; k <= 256; k <<= 1)
        for (int j = k >> 1; j > 0; j >>= 1) {
            float oth;
            if (j >= 64) {
                __syncthreads();
                s_sort[tid] = v;
                __syncthreads();
                oth = s_sort[tid ^ j];
            } else {
                oth = __shfl_xor(v, j);
            }
            bool keepmin = (((tid & k) == 0) == ((tid & j) == 0));
            v = keepmin ? fminf(v, oth) : fmaxf(v, oth);
        }
    __syncthreads();
    s_sort[tid] = v;
    int T = P * (P - 1) / 2;
    if (tid == 0) s_base = (T > 0) ? atomicAdd(&g_cursor, T) : 0;
    __syncthreads();             // publish s_sort and s_base
    int dbase = s_base;
    int carried = 0;
    for (int cb = 0; cb < T; cb += NB) {
        int t = cb + tid;
        int cnt = 0, jk = 0;
        float thr = 0.0f;
        if (t < T) {
            int a = 0;
            #pragma unroll
            for (int step = 128; step > 0; step >>= 1) {
                int na = a + step;
                if (na <= P - 2 && s_rowbase[na] <= t) a = na;
            }
            int b = a + 1 + (t - s_rowbase[a]);
            int jj = s_plist[a], kk = s_plist[b];
            thr = fmaxf(s_dd[jj], s_dd[kk]);
            jk  = jj | (kk << 8);
            cnt = ubcount(s_sort, thr);
        }
        int inc2 = block_scan_int(cnt, s_w4);
        int chunkTot = s_w4[0] + s_w4[1] + s_w4[2] + s_w4[3];
        if (t < T)
            g_trip[dbase + t] =
                make_int4(jk, __float_as_int(thr), carried + inc2 - cnt, i);
        carried += chunkTot;
    }
    if (tid == 0) g_atot[i] = carried;
}

// Dense, load-balanced emission. v2: contiguous per-wave chunks (anchor
// locality), anchor row cached in registers, lane-cooperative g_trip batch
// load + shfl broadcast, and the former k_abase fused in as a per-block
// LDS prefix scan of g_atot.
__global__ __launch_bounds__(256) void k_write(int4* __restrict__ out, int maxQuads) {
    __shared__ int s_w4[4];
    __shared__ int s_abase[NB];
    int tid = threadIdx.x;
    // Fused k_abase: exclusive prefix of per-anchor totals, kept in LDS.
    int av = g_atot[tid];
    int incl = block_scan_int(av, s_w4);
    s_abase[tid] = incl - av;
    __syncthreads();               // publish s_abase (no barriers after this)

    int wv = tid >> 6, ln = tid & 63;
    int W = (blockIdx.x << 2) | wv;            // 0..8191, flat wave id
    int Ttot = g_cursor;
    int per = (Ttot + KW_WAVES - 1) / KW_WAVES;   // contiguous chunk size
    int t0 = W * per;
    if (t0 >= Ttot) return;
    int t1 = t0 + per; if (t1 > Ttot) t1 = Ttot;
    unsigned long long lanemask = (1ULL << ln) - 1ULL;

    int cur_ai = -1;
    int base_a = 0;
    float v0 = 0.0f, v1 = 0.0f, v2 = 0.0f, v3 = 0.0f;

    for (int tb = t0; tb < t1; tb += 64) {
        int nk = t1 - tb; if (nk > 64) nk = 64;
        // lane-cooperative batch load: lane ln holds triplet tb+ln
        int4 myTr = (tb + ln < t1) ? g_trip[tb + ln] : make_int4(0, 0, 0, 0);
        for (int k = 0; k < nk; ++k) {
            int jk   = __shfl(myTr.x, k);
            int thri = __shfl(myTr.y, k);
            int toff = __shfl(myTr.z, k);
            int ai   = __shfl(myTr.w, k);
            if (ai != cur_ai) {                 // wave-uniform branch
                const float* row = g_ddneg + ai * NB;
                v0 = row[ln];       v1 = row[64 + ln];
                v2 = row[128 + ln]; v3 = row[192 + ln];
                base_a = s_abase[ai];
                cur_ai = ai;
            }
            float thr = __int_as_float(thri);
            int base = base_a + toff;
            int jj = jk & 255, kk = jk >> 8;
            bool f0 = (v0 <= thr), f1 = (v1 <= thr);
            bool f2 = (v2 <= thr), f3 = (v3 <= thr);
            unsigned long long m0 = __ballot(f0), m1 = __ballot(f1);
            unsigned long long m2 = __ballot(f2), m3 = __ballot(f3);
            int b1 = base + __popcll(m0);
            int b2 = b1 + __popcll(m1);
            int b3 = b2 + __popcll(m2);
            if (f0) { int pos = base + __popcll(m0 & lanemask);
                      if (pos < maxQuads) out[pos] = make_int4(ai, jj, kk, ln); }
            if (f1) { int pos = b1 + __popcll(m1 & lanemask);
                      if (pos < maxQuads) out[pos] = make_int4(ai, jj, kk, 64 | ln); }
            if (f2) { int pos = b2 + __popcll(m2 & lanemask);
                      if (pos < maxQuads) out[pos] = make_int4(ai, jj, kk, 128 | ln); }
            if (f3) { int pos = b3 + __popcll(m3 & lanemask);
                      if (pos < maxQuads) out[pos] = make_int4(ai, jj, kk, 192 | ln); }
        }
    }
}

extern "C" void kernel_launch(void* const* d_in, const int* in_sizes, int n_in,
                              void* d_out, int out_size, void* d_ws, size_t ws_size,
                              hipStream_t stream) {
    const float* logits = (const float*)d_in[0];
    const float* labels = (const float*)d_in[1];
    if (n_in >= 2 && in_sizes[0] == NB * NC && in_sizes[1] == NB * ND) {
        logits = (const float*)d_in[1];
        labels = (const float*)d_in[0];
    }
    int maxQuads = out_size / 4;

    k_prep <<<NB, NB, 0, stream>>>(logits, labels);
    k_count<<<NB, NB, 0, stream>>>();
    k_write<<<NB * NSPLIT, NB, 0, stream>>>((int4*)d_out, maxQuads);
}